// Round 15
// baseline (69.329 us; speedup 1.0000x reference)
//
#include <hip/hip_runtime.h>
#include <math.h>

// Problem constants: B=4, CIN=32, COUT=64, H=W=32, K=3, pad=1

typedef _Float16 half8 __attribute__((ext_vector_type(8)));
typedef _Float16 half4 __attribute__((ext_vector_type(4)));
typedef float floatx4 __attribute__((ext_vector_type(4)));

// ---------------- workspace layout ----------------
// B_f16: [var 2][tap 9][kchunk 16][n 128][16B]  = 576 KB (L2-resident)
//   n = xy*64 + o (xy: 0=cos-weights, 1=sin-weights)
//   kchunk q holds k = q*8 + j; c = k>>2 = q*2 + (j>>2), feat = k&3
//   var 0 = hi, var 1 = lo*2048
// Coalesced for the MFMA wave read (R13): lane (n16, quad) reads kchunk
// ks*4+quad at n_global*16 -> 4 contiguous 256-B segments per load inst.
// NOTE (R9 failure): B-lo CANNOT be dropped — ay abs-err ~3e-3 flips the
// atan2 branch cut at the ~50 pixels with ay~0, ax<0 -> 2pi absmax.
#define B_TAP_STRIDE (16 * 128 * 16)    // 32768
#define B_VSTRIDE (9u * 16 * 128 * 16)  // 294912

__global__ __launch_bounds__(256) void ring_prep_b(
    const float* __restrict__ probe, const float* __restrict__ outw,
    char* __restrict__ Bg) {
  int i = blockIdx.x * 256 + threadIdx.x;   // 18432 threads = 72 blocks
  int q = i & 15;                            // kchunk (no XOR)
  int n = (i >> 4) & 127;
  int tap = i >> 11;
  int o = n & 63;
  int xy = n >> 6;
  half8 hi, lo;
#pragma unroll
  for (int hf = 0; hf < 2; ++hf) {
    int c = q * 2 + hf;
    int idx = (c * 64 + o) * 9 + tap;       // ((c*COUT + o)*3 + k)*3 + l
    float th = probe[idx];
    float wvv = outw[idx];
    float sth, cth, sw, cw;
    __sincosf(th, &sth, &cth);
    __sincosf(wvv, &sw, &cw);
    float c3 = cth * fmaf(4.0f * cth, cth, -3.0f);
    float s3 = sth * fmaf(-4.0f * sth, sth, 3.0f);
    float m = xy ? sw : cw;
    float v4[4] = {0.75f * m * cth, 0.75f * m * sth, 0.25f * m * c3,
                   0.25f * m * s3};
#pragma unroll
    for (int f = 0; f < 4; ++f) {
      _Float16 hv = (_Float16)v4[f];
      hi[hf * 4 + f] = hv;
      lo[hf * 4 + f] = (_Float16)((v4[f] - (float)hv) * 2048.0f);
    }
  }
  size_t off = (((size_t)tap * 16 + q) * 128 + n) * 16;
  *(half8*)(Bg + off) = hi;
  *(half8*)(Bg + off + B_VSTRIDE) = lo;
}

// Block: one full (b,h) pixel row (32 px) x 64 n. 512 threads = 8 waves:
// wave wv -> wt = wv>>2 (pixel half), xy = (wv>>1)&1, og = wv&1.
// A-tile features (fp16 hi + lo*2048) computed in-block into swizzled LDS:
// sA [var 2][r 3][colidx 34][p 16][16B]; chunk q = p ^ (colidx & 7).
// R14: A-setup decouples load- from write-assignment — thread j loads x
// COALESCED (consecutive lanes -> consecutive w, 128-B segments) and
// ds_write_b64's the hi/lo halves to the swizzled slot; pad units filled
// by a separate constant pass.  (R12/R13 scatter: 64 lines/load-inst.)
// B (hi+lo) read coalesced from global/L2, 2-tap-deep register pipeline.
#define AL_OFF 26112   // 1632 * 16

#define BLOAD(dst, base)                          \
  do {                                            \
    dst##0 = *(const half8*)((base));             \
    dst##1 = *(const half8*)((base) + 8192);      \
    dst##2 = *(const half8*)((base) + 16384);     \
    dst##3 = *(const half8*)((base) + 24576);     \
  } while (0)

__global__ __launch_bounds__(512, 2) void ring_mfma(
    const float* __restrict__ x, const char* __restrict__ Bg,
    float* __restrict__ out) {
  __shared__ __align__(16) char sA[52224];
  __shared__ float sEx[1024];  // [wt 2][og 2][n 16][m 16]

  int blk = blockIdx.x;  // (b*32 + h)*2 + oh
  int oh = blk & 1;
  int h = (blk >> 1) & 31;
  int b = blk >> 6;
  int tid = threadIdx.x;

  int lane = tid & 63;
  int wv = tid >> 6;
  int n16 = lane & 15;
  int quad = lane >> 4;
  int wt = wv >> 2;
  int xy = (wv >> 1) & 1;
  int og = wv & 1;

  int n_global = xy * 64 + oh * 32 + og * 16 + n16;
  // lane base: kchunk = quad (ks=0) at this lane's n column
  const char* bLane = Bg + quad * 2048 + (size_t)n_global * 16;

  // ---- prefetch taps 0 and 1 (hi+lo) — in flight across the A-setup ----
  half8 BcH0, BcH1, BcH2, BcH3, BcL0, BcL1, BcL2, BcL3;   // tap t
  half8 BnH0, BnH1, BnH2, BnH3, BnL0, BnL1, BnL2, BnL3;   // tap t+1
  half8 BtH0, BtH1, BtH2, BtH3, BtL0, BtL1, BtL2, BtL3;   // tap t+2
  BLOAD(BcH, bLane);
  BLOAD(BcL, bLane + B_VSTRIDE);
  BLOAD(BnH, bLane + B_TAP_STRIDE);
  BLOAD(BnL, bLane + B_TAP_STRIDE + B_VSTRIDE);

  // ---- A-setup phase 1: pad units -> (1,0,1,0) hi, 0 lo ----
  // Unit (r, colidx, p) is pad iff hs = h+r-1 or wsx = colidx-1 out of range.
  {
    half8 padhi;
#pragma unroll
    for (int f = 0; f < 8; ++f) padhi[f] = (_Float16)((f & 1) ? 0.0f : 1.0f);
    half8 padlo;
#pragma unroll
    for (int f = 0; f < 8; ++f) padlo[f] = (_Float16)0.0f;
#pragma unroll
    for (int it = 0; it < 4; ++it) {
      int u = tid + it * 512;
      if (u >= 1632) continue;
      int t = u >> 4;
      int colidx = t % 34;
      int r = t / 34;
      int hs = h + r - 1;
      int wsx = colidx - 1;
      bool pad = ((unsigned)hs >= 32u) || ((unsigned)wsx >= 32u);
      if (!pad) continue;
      *(half8*)(sA + u * 16) = padhi;
      *(half8*)(sA + u * 16 + AL_OFF) = padlo;
    }
  }

  // ---- A-setup phase 2: valid elements, coalesced loads ----
  // element e = (c*3 + r)*32 + wsx ; one x value -> one (unit, half) slot:
  //   colidx = wsx+1, p = (c>>1) ^ (colidx&7), hf = c&1
  {
#pragma unroll
    for (int it = 0; it < 6; ++it) {
      int e = tid + it * 512;     // 0..3071
      int wsx = e & 31;
      int t = e >> 5;             // 0..95
      int r = t % 3;
      int c = t / 3;              // 0..31
      int hs = h + r - 1;
      if ((unsigned)hs >= 32u) continue;   // row pad handled in phase 1
      float pv = x[((b * 32 + c) * 32 + hs) * 32 + wsx];
      float s1, c1;
      __sincosf(pv, &s1, &c1);
      float c3 = c1 * fmaf(4.0f * c1, c1, -3.0f);
      float s3 = s1 * fmaf(-4.0f * s1, s1, 3.0f);
      float v4[4] = {c1, s1, c3, s3};
      half4 hi4, lo4;
#pragma unroll
      for (int f = 0; f < 4; ++f) {
        _Float16 hv = (_Float16)v4[f];
        hi4[f] = hv;
        lo4[f] = (_Float16)((v4[f] - (float)hv) * 2048.0f);
      }
      int colidx = wsx + 1;
      int p = (c >> 1) ^ (colidx & 7);
      int hf = c & 1;
      int off = ((r * 34 + colidx) * 16 + p) * 16 + hf * 8;
      *(half4*)(sA + off) = hi4;
      *(half4*)(sA + off + AL_OFF) = lo4;
    }
  }

  floatx4 acc0 = {0.f, 0.f, 0.f, 0.f};   // Ah*Bh
  floatx4 acc1 = {0.f, 0.f, 0.f, 0.f};   // Al*Bh
  floatx4 acc2 = {0.f, 0.f, 0.f, 0.f};   // Ah*Bl

  __syncthreads();  // A tile visible; tap loop is barrier-free

#pragma unroll
  for (int tap = 0; tap < 9; ++tap) {
    // prefetch tap+2's B (hi+lo) into the third buffer
    if (tap < 7) {
      const char* bt = bLane + (size_t)(tap + 2) * B_TAP_STRIDE;
      BLOAD(BtH, bt);
      BLOAD(BtL, bt + B_VSTRIDE);
    }

    int dk = tap / 3;
    int l = tap - dk * 3;
    int colidx = wt * 16 + n16 + l;  // pixel-within-row + l; akey unchanged
    int akey = colidx & 7;           // by wt*16 since 16 % 8 == 0
    const char* aH = sA + (dk * 34 + colidx) * 256;
    const char* aL = aH + AL_OFF;

#pragma unroll
    for (int ks = 0; ks < 4; ++ks) {
      int pa = ((ks * 4 + quad) ^ akey) * 16;
      half8 Ah = *(const half8*)(aH + pa);
      half8 Al = *(const half8*)(aL + pa);
      half8 Bh = (ks == 0) ? BcH0 : (ks == 1) ? BcH1 : (ks == 2) ? BcH2 : BcH3;
      half8 Bl = (ks == 0) ? BcL0 : (ks == 1) ? BcL1 : (ks == 2) ? BcL2 : BcL3;
      acc0 = __builtin_amdgcn_mfma_f32_16x16x32_f16(Ah, Bh, acc0, 0, 0, 0);
      acc1 = __builtin_amdgcn_mfma_f32_16x16x32_f16(Al, Bh, acc1, 0, 0, 0);
      acc2 = __builtin_amdgcn_mfma_f32_16x16x32_f16(Ah, Bl, acc2, 0, 0, 0);
    }
    // rotate the 3-stage pipeline (fully unrolled -> register renaming)
    BcH0 = BnH0; BcH1 = BnH1; BcH2 = BnH2; BcH3 = BnH3;
    BcL0 = BnL0; BcL1 = BnL1; BcL2 = BnL2; BcL3 = BnL3;
    BnH0 = BtH0; BnH1 = BtH1; BnH2 = BtH2; BnH3 = BtH3;
    BnL0 = BtL0; BnL1 = BtL1; BnL2 = BtL2; BnL3 = BtL3;
  }

  floatx4 fin = acc0 + (acc1 + acc2) * (1.0f / 2048.0f);

  // ---- epilogue: y-waves hand ay to x-waves (same wt,og); atan2 + store ----
  __syncthreads();
  if (xy == 1) {
#pragma unroll
    for (int r = 0; r < 4; ++r)
      sEx[((wt * 2 + og) * 16 + n16) * 16 + quad * 4 + r] = fin[r];
  }
  __syncthreads();
  if (xy == 0) {
    int o = oh * 32 + og * 16 + n16;
    float4 res;
    float* rp = (float*)&res;
#pragma unroll
    for (int r = 0; r < 4; ++r) {
      int m = quad * 4 + r;
      float ay = sEx[((wt * 2 + og) * 16 + n16) * 16 + m];
      rp[r] = atan2f(ay, fin[r]);
    }
    float* dst = out + (((size_t)(b * 64 + o) * 32 + h) * 32 + wt * 16 + quad * 4);
    *(float4*)dst = res;
  }
}

extern "C" void kernel_launch(void* const* d_in, const int* in_sizes, int n_in,
                              void* d_out, int out_size, void* d_ws, size_t ws_size,
                              hipStream_t stream) {
  const float* x = (const float*)d_in[0];
  const float* probe = (const float*)d_in[1];
  const float* outw = (const float*)d_in[2];
  char* Bg = (char*)d_ws;
  float* out = (float*)d_out;

  ring_prep_b<<<72, 256, 0, stream>>>(probe, outw, Bg);
  ring_mfma<<<256, 512, 0, stream>>>(x, Bg, out);
}